// Round 1
// baseline (131.079 us; speedup 1.0000x reference)
//
#include <hip/hip_runtime.h>
#include <hip/hip_bf16.h>

typedef unsigned short u16x8 __attribute__((ext_vector_type(8)));
typedef __bf16 bf16x8 __attribute__((ext_vector_type(8)));
typedef float f32x4 __attribute__((ext_vector_type(4)));

#define NODE_DIM 128
#define HID 64

__device__ __forceinline__ unsigned short f2bf(float f) {
  union { float f; unsigned int u; } v; v.f = f;
  unsigned int u = v.u;
  u += 0x7fffu + ((u >> 16) & 1u);   // round-to-nearest-even
  return (unsigned short)(u >> 16);
}
__device__ __forceinline__ float bf2f(unsigned short s) {
  union { unsigned int u; float f; } v; v.u = ((unsigned int)s) << 16;
  return v.f;
}

// Repack W1 (256x64 row-major fp32) into Wt[j][k] bf16, j,k in [0,128):
//   j<64 : Wt[j][k] = W1[k][j]        (first half of concat -> x[row])
//   j>=64: Wt[j][k] = W1[k+128][j-64] (second half          -> x[col])
// k-contiguous so B-fragments load as single b128s.
__global__ void prep_wt(const float* __restrict__ W1, unsigned short* __restrict__ Wt) {
  for (int i = blockIdx.x * blockDim.x + threadIdx.x; i < 128 * 128;
       i += gridDim.x * blockDim.x) {
    int j = i >> 7, k = i & 127;
    float w = (j < 64) ? W1[k * 64 + j] : W1[(k + 128) * 64 + (j - 64)];
    Wt[i] = f2bf(w);
  }
}

// PQ[n][j] = sum_k x[n][k] * Wt[j][k]   (bf16 MFMA, fp32 accum, bf16 store)
__global__ __launch_bounds__(256) void gemm_pq(const float* __restrict__ x,
                                               const unsigned short* __restrict__ Wt,
                                               unsigned short* __restrict__ PQ,
                                               int n_nodes) {
  __shared__ unsigned short xs[64][136];   // +8 pad: 2-way bank alias (free)
  __shared__ unsigned short bs[128][136];
  const int tid = threadIdx.x;
  const int row0 = blockIdx.x * 64;

  // stage Wt (bf16 128x128) -> bs, 16B chunks, coalesced
  for (int i = tid; i < 128 * 16; i += 256) {
    int j = i >> 4, c = i & 15;
    *(u16x8*)&bs[j][c * 8] = *(const u16x8*)&Wt[j * 128 + c * 8];
  }
  // stage x rows fp32 -> bf16 LDS
  for (int i = tid; i < 64 * 32; i += 256) {
    int r = i >> 5, c = i & 31;
    int gr = row0 + r;
    float4 v = make_float4(0.f, 0.f, 0.f, 0.f);
    if (gr < n_nodes) v = *(const float4*)&x[(size_t)gr * NODE_DIM + c * 4];
    xs[r][c * 4 + 0] = f2bf(v.x); xs[r][c * 4 + 1] = f2bf(v.y);
    xs[r][c * 4 + 2] = f2bf(v.z); xs[r][c * 4 + 3] = f2bf(v.w);
  }
  __syncthreads();

  const int wave = tid >> 6, lane = tid & 63;
  const int m = lane & 15, q = lane >> 4;
  const int wrow = wave * 16;  // each wave: 16 rows x all 128 cols

  f32x4 acc[8];
  #pragma unroll
  for (int t = 0; t < 8; t++) acc[t] = f32x4{0.f, 0.f, 0.f, 0.f};

  #pragma unroll
  for (int kk = 0; kk < 4; kk++) {
    const int k0 = kk * 32;
    // A[m=lane&15][k = q*8 + j]  (m120-verified layout)
    bf16x8 a = __builtin_bit_cast(bf16x8, *(const u16x8*)&xs[wrow + m][k0 + q * 8]);
    #pragma unroll
    for (int t = 0; t < 8; t++) {
      // B[k = q*8 + j][n = t*16 + (lane&15)]  (Wt stored transposed -> contiguous k)
      bf16x8 b = __builtin_bit_cast(bf16x8, *(const u16x8*)&bs[t * 16 + m][k0 + q * 8]);
      acc[t] = __builtin_amdgcn_mfma_f32_16x16x32_bf16(a, b, acc[t], 0, 0, 0);
    }
  }

  // C/D: col = lane&15, row = q*4 + reg  (m89-verified)
  #pragma unroll
  for (int t = 0; t < 8; t++) {
    #pragma unroll
    for (int r = 0; r < 4; r++) {
      int gr = row0 + wrow + q * 4 + r;
      if (gr < n_nodes) PQ[(size_t)gr * 128 + t * 16 + m] = f2bf(acc[t][r]);
    }
  }
}

// 8 lanes per edge: lane l handles hidden dims [l*8, l*8+8)
__global__ __launch_bounds__(256) void edge_mlp(const int* __restrict__ ei,
                                                const unsigned short* __restrict__ PQ,
                                                const float* __restrict__ b1,
                                                const float* __restrict__ W2,
                                                const float* __restrict__ b2,
                                                float* __restrict__ out, int E) {
  const int t = blockIdx.x * blockDim.x + threadIdx.x;
  const int l = t & 7;
  float w2r[8], b1r[8];
  #pragma unroll
  for (int i = 0; i < 8; i++) { w2r[i] = W2[l * 8 + i]; b1r[i] = b1[l * 8 + i]; }
  const float bias2 = b2[0];
  const int ngroups = (gridDim.x * blockDim.x) >> 3;
  for (int e = t >> 3; e < E; e += ngroups) {
    int row = ei[e];
    int col = ei[E + e];
    u16x8 pu = *(const u16x8*)&PQ[(size_t)row * 128 + l * 8];
    u16x8 qu = *(const u16x8*)&PQ[(size_t)col * 128 + 64 + l * 8];
    float partial = 0.f;
    #pragma unroll
    for (int i = 0; i < 8; i++) {
      float h = bf2f(pu[i]) + bf2f(qu[i]) + b1r[i];
      h = fmaxf(h, 0.f);
      partial = fmaf(h, w2r[i], partial);
    }
    partial += __shfl_xor(partial, 1);
    partial += __shfl_xor(partial, 2);
    partial += __shfl_xor(partial, 4);
    if (l == 0) out[e] = 1.f / (1.f + __expf(-(partial + bias2)));
  }
}

extern "C" void kernel_launch(void* const* d_in, const int* in_sizes, int n_in,
                              void* d_out, int out_size, void* d_ws, size_t ws_size,
                              hipStream_t stream) {
  const float* x  = (const float*)d_in[0];
  const int*   ei = (const int*)d_in[1];
  const float* W1 = (const float*)d_in[2];
  const float* b1 = (const float*)d_in[3];
  const float* W2 = (const float*)d_in[4];
  const float* b2 = (const float*)d_in[5];
  float* out = (float*)d_out;
  const int n_nodes = in_sizes[0] / NODE_DIM;
  const int E = in_sizes[1] / 2;

  // ws layout: Wt bf16 [128*128] @ 0 (32 KB), PQ bf16 [n_nodes*128] @ 32768 (25.6 MB)
  unsigned short* Wt = (unsigned short*)d_ws;
  unsigned short* PQ = (unsigned short*)((char*)d_ws + 32768);

  prep_wt<<<16, 256, 0, stream>>>(W1, Wt);
  gemm_pq<<<(n_nodes + 63) / 64, 256, 0, stream>>>(x, Wt, PQ, n_nodes);
  edge_mlp<<<2048, 256, 0, stream>>>(ei, PQ, b1, W2, b2, out, E);
}